// Round 3
// baseline (123.587 us; speedup 1.0000x reference)
//
#include <hip/hip_runtime.h>

#define TDIM 4096
#define SBAR() __builtin_amdgcn_sched_barrier(0)

// frame layout: f[0..8]=R (row major), f[9..11]=pos, f[12..15]=parent raw quat
__device__ __forceinline__ void fk_step(float* __restrict__ f,
                                        const float* __restrict__ q,
                                        const float* __restrict__ off) {
  const float pw = f[12], px = f[13], py = f[14], pz = f[15];
  // loc = conj(parent_q) * q
  float lw = pw*q[0] + px*q[1] + py*q[2] + pz*q[3];
  float lx = pw*q[1] - px*q[0] - py*q[3] + pz*q[2];
  float ly = pw*q[2] + px*q[3] - py*q[0] - pz*q[1];
  float lz = pw*q[3] - px*q[2] + py*q[1] - pz*q[0];
  float n2 = lw*lw + lx*lx + ly*ly + lz*lz;
  float inv = rsqrtf(fmaxf(n2, 1e-16f));
  lw *= inv; lx *= inv; ly *= inv; lz *= inv;
  float xx = lx*lx, yy = ly*ly, zz = lz*lz;
  float xy = lx*ly, xz = lx*lz, yz = ly*lz;
  float wx = lw*lx, wy = lw*ly, wz = lw*lz;
  float m0 = 1.0f-2.0f*(yy+zz), m1 = 2.0f*(xy-wz),      m2 = 2.0f*(xz+wy);
  float m3 = 2.0f*(xy+wz),      m4 = 1.0f-2.0f*(xx+zz), m5 = 2.0f*(yz-wx);
  float m6 = 2.0f*(xz-wy),      m7 = 2.0f*(yz+wx),      m8 = 1.0f-2.0f*(xx+yy);
  f[9]  += f[0]*off[0] + f[1]*off[1] + f[2]*off[2];
  f[10] += f[3]*off[0] + f[4]*off[1] + f[5]*off[2];
  f[11] += f[6]*off[0] + f[7]*off[1] + f[8]*off[2];
  float r0 = f[0]*m0 + f[1]*m3 + f[2]*m6;
  float r1 = f[0]*m1 + f[1]*m4 + f[2]*m7;
  float r2 = f[0]*m2 + f[1]*m5 + f[2]*m8;
  float r3 = f[3]*m0 + f[4]*m3 + f[5]*m6;
  float r4 = f[3]*m1 + f[4]*m4 + f[5]*m7;
  float r5 = f[3]*m2 + f[4]*m5 + f[5]*m8;
  float r6 = f[6]*m0 + f[7]*m3 + f[8]*m6;
  float r7 = f[6]*m1 + f[7]*m4 + f[8]*m7;
  float r8 = f[6]*m2 + f[7]*m5 + f[8]*m8;
  f[0]=r0; f[1]=r1; f[2]=r2; f[3]=r3; f[4]=r4; f[5]=r5; f[6]=r6; f[7]=r7; f[8]=r8;
  f[12]=q[0]; f[13]=q[1]; f[14]=q[2]; f[15]=q[3];
}

__global__ __launch_bounds__(256) void fk_loss_kernel(
    const float* __restrict__ ik,   // (32, 168, 4096)
    const float* __restrict__ dec,  // (32, 176, 4096)
    const float* __restrict__ tgt,  // (32, 176, 4096)
    const float* __restrict__ mean, // (176,)
    const float* __restrict__ stdv, // (176,)
    const float* __restrict__ offs, // (22, 3)
    float* __restrict__ out)
{
  __shared__ float s_mean[176];
  __shared__ float s_std[176];
  __shared__ float s_off[66];
  __shared__ float s_wsum[4];
  const int tid = threadIdx.x;
  for (int i = tid; i < 176; i += 256) { s_mean[i] = mean[i]; s_std[i] = stdv[i]; }
  for (int i = tid; i < 66; i += 256) s_off[i] = offs[i];
  __syncthreads();

  // role split: even blocks = chains A+B (joints 1..8); odd = chain C+branches (9..21)
  const int role = blockIdx.x & 1;
  const int idx = (blockIdx.x >> 1) * 256 + tid;   // 0 .. 131071
  const int b = idx >> 12;
  const int t = idx & 4095;
  const float* __restrict__ pik  = ik  + ((size_t)b * 168) * TDIM + t;
  const float* __restrict__ pdec = dec + ((size_t)b * 176) * TDIM + t;
  const float* __restrict__ ptgt = tgt + ((size_t)b * 176) * TDIM + t;

  float see_p = 0.f, see_m = 0.f, srg_p = 0.f, srg_m = 0.f;

  float fik[16], fdec[16], ftgt[16];
  float rq[4];
  // stage buffers: [0..3] ik raw, [4..7] dec raw, [8..11] tgt raw,
  //                [12..15] std, [16..19] mean, [20..22] off
  float A[23], B[23];

#define LOADST(buf, j)                                                         \
  { _Pragma("unroll")                                                          \
    for (int c = 0; c < 4; c++) buf[c]      = pik [(((j)-1)*8 + c) * TDIM];    \
    _Pragma("unroll")                                                          \
    for (int c = 0; c < 4; c++) buf[4 + c]  = pdec[(((j)*8)   + c) * TDIM];    \
    _Pragma("unroll")                                                          \
    for (int c = 0; c < 4; c++) buf[8 + c]  = ptgt[(((j)*8)   + c) * TDIM];    \
    _Pragma("unroll")                                                          \
    for (int c = 0; c < 4; c++) buf[12 + c] = s_std[(j)*8 + c];                \
    _Pragma("unroll")                                                          \
    for (int c = 0; c < 4; c++) buf[16 + c] = s_mean[(j)*8 + c];               \
    _Pragma("unroll")                                                          \
    for (int c = 0; c < 3; c++) buf[20 + c] = s_off[(j)*3 + c]; }

#define COMP(buf, IS_EE)                                                       \
  { float qi[4], qd[4], qt[4];                                                 \
    _Pragma("unroll")                                                          \
    for (int c = 0; c < 4; c++) {                                              \
      qi[c] = fmaf(buf[c],     buf[12+c], buf[16+c]);                          \
      qd[c] = fmaf(buf[4+c],   buf[12+c], buf[16+c]);                          \
      qt[c] = fmaf(buf[8+c],   buf[12+c], buf[16+c]);                          \
    }                                                                          \
    fk_step(fik,  qi, buf + 20);                                               \
    fk_step(fdec, qd, buf + 20);                                               \
    fk_step(ftgt, qt, buf + 20);                                               \
    if (IS_EE) {                                                               \
      _Pragma("unroll")                                                        \
      for (int c = 0; c < 3; c++) { float d = fik[9+c] - ftgt[9+c]; see_p = fmaf(d, d, see_p); } \
      _Pragma("unroll")                                                        \
      for (int c = 0; c < 9; c++) { float d = fik[c]   - ftgt[c];   see_m = fmaf(d, d, see_m); } \
    } else {                                                                   \
      _Pragma("unroll")                                                        \
      for (int c = 0; c < 3; c++) { float d = fdec[9+c] - fik[9+c]; srg_p = fmaf(d, d, srg_p); } \
      _Pragma("unroll")                                                        \
      for (int c = 0; c < 9; c++) { float d = fdec[c]   - fik[c];   srg_m = fmaf(d, d, srg_m); } \
    } }

#define RESET()                                                                \
  { _Pragma("unroll")                                                          \
    for (int c = 0; c < 16; c++) { fik[c] = 0.f; fdec[c] = 0.f; ftgt[c] = 0.f; } \
    fik[0]=fik[4]=fik[8]=1.f; fdec[0]=fdec[4]=fdec[8]=1.f; ftgt[0]=ftgt[4]=ftgt[8]=1.f; \
    fik[12]=1.f; fdec[12]=1.f;                                                 \
    ftgt[12]=rq[0]; ftgt[13]=rq[1]; ftgt[14]=rq[2]; ftgt[15]=rq[3]; }

  float rqr[4], rqs[4], rqm[4];
  #pragma unroll
  for (int c = 0; c < 4; c++) { rqr[c] = ptgt[c * TDIM]; rqs[c] = s_std[c]; rqm[c] = s_mean[c]; }

  if (role == 0) {
    // ---- chains A (1..4) and B (5..8) ----
    LOADST(A, 1);
    SBAR();
    #pragma unroll
    for (int c = 0; c < 4; c++) rq[c] = fmaf(rqr[c], rqs[c], rqm[c]);
    RESET();
    LOADST(B, 2);  COMP(A, false); SBAR();            // joint 1
    LOADST(A, 3);  COMP(B, false); SBAR();            // joint 2
    LOADST(B, 4);  COMP(A, false); SBAR();            // joint 3
    LOADST(A, 5);  COMP(B, true);  RESET(); SBAR();   // joint 4 EE
    LOADST(B, 6);  COMP(A, false); SBAR();            // joint 5
    LOADST(A, 7);  COMP(B, false); SBAR();            // joint 6
    LOADST(B, 8);  COMP(A, false); SBAR();            // joint 7
    COMP(B, true);                                    // joint 8 EE
  } else {
    // ---- chain C (9..11, branch) -> {12,13} {14..17} {18..21} ----
    float sik[16], sdec[16], stgt[16];
    LOADST(A, 9);
    SBAR();
    #pragma unroll
    for (int c = 0; c < 4; c++) rq[c] = fmaf(rqr[c], rqs[c], rqm[c]);
    RESET();
    LOADST(B, 10); COMP(A, false); SBAR();            // joint 9
    LOADST(A, 11); COMP(B, false); SBAR();            // joint 10
    LOADST(B, 12); COMP(A, false);                    // joint 11 (branch point)
    #pragma unroll
    for (int c = 0; c < 16; c++) { sik[c]=fik[c]; sdec[c]=fdec[c]; stgt[c]=ftgt[c]; }
    SBAR();
    LOADST(A, 13); COMP(B, false); SBAR();            // joint 12
    LOADST(B, 14); COMP(A, true);                     // joint 13 EE
    #pragma unroll
    for (int c = 0; c < 16; c++) { fik[c]=sik[c]; fdec[c]=sdec[c]; ftgt[c]=stgt[c]; }
    SBAR();
    LOADST(A, 15); COMP(B, false); SBAR();            // joint 14
    LOADST(B, 16); COMP(A, false); SBAR();            // joint 15
    LOADST(A, 17); COMP(B, false); SBAR();            // joint 16
    LOADST(B, 18); COMP(A, true);                     // joint 17 EE
    #pragma unroll
    for (int c = 0; c < 16; c++) { fik[c]=sik[c]; fdec[c]=sdec[c]; ftgt[c]=stgt[c]; }
    SBAR();
    LOADST(A, 19); COMP(B, false); SBAR();            // joint 18
    LOADST(B, 20); COMP(A, false); SBAR();            // joint 19
    LOADST(A, 21); COMP(B, false); SBAR();            // joint 20
    COMP(A, true);                                    // joint 21 EE
  }

#undef LOADST
#undef COMP
#undef RESET

  // weights: see_p/(BT*15) + see_m/(BT*45) + 0.1*(srg_p/(BT*48) + srg_m/(BT*144))
  const float W1 = 1.0f / 1966080.0f;
  const float W2 = 1.0f / 5898240.0f;
  const float W3 = 0.1f / 6291456.0f;
  const float W4 = 0.1f / 18874368.0f;
  float val = see_p * W1 + see_m * W2 + srg_p * W3 + srg_m * W4;

  #pragma unroll
  for (int o = 32; o > 0; o >>= 1) val += __shfl_down(val, o, 64);
  const int wid = tid >> 6, lane = tid & 63;
  if (lane == 0) s_wsum[wid] = val;
  __syncthreads();
  if (tid == 0) atomicAdd(out, s_wsum[0] + s_wsum[1] + s_wsum[2] + s_wsum[3]);
}

extern "C" void kernel_launch(void* const* d_in, const int* in_sizes, int n_in,
                              void* d_out, int out_size, void* d_ws, size_t ws_size,
                              hipStream_t stream) {
  const float* ik   = (const float*)d_in[1];
  const float* dec  = (const float*)d_in[2];
  const float* tgt  = (const float*)d_in[3];
  const float* mean = (const float*)d_in[4];
  const float* stdv = (const float*)d_in[5];
  const float* offs = (const float*)d_in[6];
  float* out = (float*)d_out;

  hipMemsetAsync(out, 0, sizeof(float), stream);
  fk_loss_kernel<<<dim3(1024), dim3(256), 0, stream>>>(ik, dec, tgt, mean, stdv, offs, out);
}

// Round 4
// 35.384 us; speedup vs baseline: 3.4927x; 3.4927x over previous
//
#include <hip/hip_runtime.h>

#define TDIM 4096
#define SBAR() __builtin_amdgcn_sched_barrier(0)

// frame layout: f[0..8]=R (row major), f[9..11]=pos, f[12..15]=parent raw quat
__device__ __forceinline__ void fk_step(float* __restrict__ f,
                                        const float* __restrict__ q,
                                        float o0, float o1, float o2) {
  const float pw = f[12], px = f[13], py = f[14], pz = f[15];
  // loc = conj(parent_q) * q
  float lw = pw*q[0] + px*q[1] + py*q[2] + pz*q[3];
  float lx = pw*q[1] - px*q[0] - py*q[3] + pz*q[2];
  float ly = pw*q[2] + px*q[3] - py*q[0] - pz*q[1];
  float lz = pw*q[3] - px*q[2] + py*q[1] - pz*q[0];
  float n2 = lw*lw + lx*lx + ly*ly + lz*lz;
  float inv = rsqrtf(fmaxf(n2, 1e-16f));
  lw *= inv; lx *= inv; ly *= inv; lz *= inv;
  float xx = lx*lx, yy = ly*ly, zz = lz*lz;
  float xy = lx*ly, xz = lx*lz, yz = ly*lz;
  float wx = lw*lx, wy = lw*ly, wz = lw*lz;
  float m0 = 1.0f-2.0f*(yy+zz), m1 = 2.0f*(xy-wz),      m2 = 2.0f*(xz+wy);
  float m3 = 2.0f*(xy+wz),      m4 = 1.0f-2.0f*(xx+zz), m5 = 2.0f*(yz-wx);
  float m6 = 2.0f*(xz-wy),      m7 = 2.0f*(yz+wx),      m8 = 1.0f-2.0f*(xx+yy);
  f[9]  += f[0]*o0 + f[1]*o1 + f[2]*o2;
  f[10] += f[3]*o0 + f[4]*o1 + f[5]*o2;
  f[11] += f[6]*o0 + f[7]*o1 + f[8]*o2;
  float r0 = f[0]*m0 + f[1]*m3 + f[2]*m6;
  float r1 = f[0]*m1 + f[1]*m4 + f[2]*m7;
  float r2 = f[0]*m2 + f[1]*m5 + f[2]*m8;
  float r3 = f[3]*m0 + f[4]*m3 + f[5]*m6;
  float r4 = f[3]*m1 + f[4]*m4 + f[5]*m7;
  float r5 = f[3]*m2 + f[4]*m5 + f[5]*m8;
  float r6 = f[6]*m0 + f[7]*m3 + f[8]*m6;
  float r7 = f[6]*m1 + f[7]*m4 + f[8]*m7;
  float r8 = f[6]*m2 + f[7]*m5 + f[8]*m8;
  f[0]=r0; f[1]=r1; f[2]=r2; f[3]=r3; f[4]=r4; f[5]=r5; f[6]=r6; f[7]=r7; f[8]=r8;
  f[12]=q[0]; f[13]=q[1]; f[14]=q[2]; f[15]=q[3];
}

__global__ __launch_bounds__(256, 4) void fk_loss_kernel(
    const float* __restrict__ ik,   // (32, 168, 4096)
    const float* __restrict__ dec,  // (32, 176, 4096)
    const float* __restrict__ tgt,  // (32, 176, 4096)
    const float* __restrict__ mean, // (176,)
    const float* __restrict__ stdv, // (176,)
    const float* __restrict__ offs, // (22, 3)
    float* __restrict__ out)
{
  __shared__ float s_mean[176];
  __shared__ float s_std[176];
  __shared__ float s_save[36 * 256];   // branch save: [i]*256 + tid, conflict-free
  __shared__ float s_wsum[4];
  const int tid = threadIdx.x;
  for (int i = tid; i < 176; i += 256) { s_mean[i] = mean[i]; s_std[i] = stdv[i]; }
  __syncthreads();

  const int idx = blockIdx.x * 256 + tid;   // 0 .. 131071
  const int b = idx >> 12;
  const int t = idx & 4095;
  const float* __restrict__ pik  = ik  + ((size_t)b * 168) * TDIM + t;
  const float* __restrict__ pdec = dec + ((size_t)b * 176) * TDIM + t;
  const float* __restrict__ ptgt = tgt + ((size_t)b * 176) * TDIM + t;

  float see_p = 0.f, see_m = 0.f, srg_p = 0.f, srg_m = 0.f;

  float fik[16], fdec[16], ftgt[16];
  float rq[4];
  float qsv[12];        // parent-quat part of the joint-11 save (stays in VGPR)
  float A[12], B[12];   // stage buffers: [0..3] ik raw, [4..7] dec raw, [8..11] tgt raw

#define LOADST(buf, j)                                                         \
  { _Pragma("unroll")                                                          \
    for (int c = 0; c < 4; c++) buf[c]      = pik [(((j)-1)*8 + c) * TDIM];    \
    _Pragma("unroll")                                                          \
    for (int c = 0; c < 4; c++) buf[4 + c]  = pdec[(((j)*8)   + c) * TDIM];    \
    _Pragma("unroll")                                                          \
    for (int c = 0; c < 4; c++) buf[8 + c]  = ptgt[(((j)*8)   + c) * TDIM]; }

#define COMP(buf, j, IS_EE)                                                    \
  { float qi[4], qd[4], qt[4];                                                 \
    _Pragma("unroll")                                                          \
    for (int c = 0; c < 4; c++) {                                              \
      const float sd = s_std[(j)*8 + c], mn = s_mean[(j)*8 + c];               \
      qi[c] = fmaf(buf[c],     sd, mn);                                        \
      qd[c] = fmaf(buf[4+c],   sd, mn);                                        \
      qt[c] = fmaf(buf[8+c],   sd, mn);                                        \
    }                                                                          \
    const float o0 = offs[(j)*3], o1 = offs[(j)*3+1], o2 = offs[(j)*3+2];      \
    fk_step(fik,  qi, o0, o1, o2);                                             \
    fk_step(fdec, qd, o0, o1, o2);                                             \
    fk_step(ftgt, qt, o0, o1, o2);                                             \
    if (IS_EE) {                                                               \
      _Pragma("unroll")                                                        \
      for (int c = 0; c < 3; c++) { float d = fik[9+c] - ftgt[9+c]; see_p = fmaf(d, d, see_p); } \
      _Pragma("unroll")                                                        \
      for (int c = 0; c < 9; c++) { float d = fik[c]   - ftgt[c];   see_m = fmaf(d, d, see_m); } \
    } else {                                                                   \
      _Pragma("unroll")                                                        \
      for (int c = 0; c < 3; c++) { float d = fdec[9+c] - fik[9+c]; srg_p = fmaf(d, d, srg_p); } \
      _Pragma("unroll")                                                        \
      for (int c = 0; c < 9; c++) { float d = fdec[c]   - fik[c];   srg_m = fmaf(d, d, srg_m); } \
    } }

#define RESET()                                                                \
  { _Pragma("unroll")                                                          \
    for (int c = 0; c < 16; c++) { fik[c] = 0.f; fdec[c] = 0.f; ftgt[c] = 0.f; } \
    fik[0]=fik[4]=fik[8]=1.f; fdec[0]=fdec[4]=fdec[8]=1.f; ftgt[0]=ftgt[4]=ftgt[8]=1.f; \
    fik[12]=1.f; fdec[12]=1.f;                                                 \
    ftgt[12]=rq[0]; ftgt[13]=rq[1]; ftgt[14]=rq[2]; ftgt[15]=rq[3]; }

#define SAVE()                                                                 \
  { _Pragma("unroll")                                                          \
    for (int c = 0; c < 12; c++) {                                             \
      s_save[c*256 + tid]      = fik[c];                                       \
      s_save[(12+c)*256 + tid] = fdec[c];                                      \
      s_save[(24+c)*256 + tid] = ftgt[c];                                      \
    }                                                                          \
    _Pragma("unroll")                                                          \
    for (int c = 0; c < 4; c++) { qsv[c]=fik[12+c]; qsv[4+c]=fdec[12+c]; qsv[8+c]=ftgt[12+c]; } }

#define RESTORE()                                                              \
  { _Pragma("unroll")                                                          \
    for (int c = 0; c < 12; c++) {                                             \
      fik[c]  = s_save[c*256 + tid];                                           \
      fdec[c] = s_save[(12+c)*256 + tid];                                      \
      ftgt[c] = s_save[(24+c)*256 + tid];                                      \
    }                                                                          \
    _Pragma("unroll")                                                          \
    for (int c = 0; c < 4; c++) { fik[12+c]=qsv[c]; fdec[12+c]=qsv[4+c]; ftgt[12+c]=qsv[8+c]; } }

  // ---- prime pipeline ----
  float rqr[4];
  #pragma unroll
  for (int c = 0; c < 4; c++) rqr[c] = ptgt[c * TDIM];
  LOADST(A, 1);
  SBAR();
  #pragma unroll
  for (int c = 0; c < 4; c++) rq[c] = fmaf(rqr[c], s_std[c], s_mean[c]);
  RESET();
  LOADST(B, 2);  COMP(A, 1,  false); SBAR();
  LOADST(A, 3);  COMP(B, 2,  false); SBAR();
  LOADST(B, 4);  COMP(A, 3,  false); SBAR();
  LOADST(A, 5);  COMP(B, 4,  true);  RESET(); SBAR();
  LOADST(B, 6);  COMP(A, 5,  false); SBAR();
  LOADST(A, 7);  COMP(B, 6,  false); SBAR();
  LOADST(B, 8);  COMP(A, 7,  false); SBAR();
  LOADST(A, 9);  COMP(B, 8,  true);  RESET(); SBAR();
  LOADST(B, 10); COMP(A, 9,  false); SBAR();
  LOADST(A, 11); COMP(B, 10, false); SBAR();
  LOADST(B, 12); COMP(A, 11, false); SAVE(); SBAR();
  LOADST(A, 13); COMP(B, 12, false); SBAR();
  LOADST(B, 14); COMP(A, 13, true);  RESTORE(); SBAR();
  LOADST(A, 15); COMP(B, 14, false); SBAR();
  LOADST(B, 16); COMP(A, 15, false); SBAR();
  LOADST(A, 17); COMP(B, 16, false); SBAR();
  LOADST(B, 18); COMP(A, 17, true);  RESTORE(); SBAR();
  LOADST(A, 19); COMP(B, 18, false); SBAR();
  LOADST(B, 20); COMP(A, 19, false); SBAR();
  LOADST(A, 21); COMP(B, 20, false); SBAR();
  COMP(A, 21, true);

#undef LOADST
#undef COMP
#undef RESET
#undef SAVE
#undef RESTORE

  // weights: see_p/(BT*15) + see_m/(BT*45) + 0.1*(srg_p/(BT*48) + srg_m/(BT*144))
  const float W1 = 1.0f / 1966080.0f;
  const float W2 = 1.0f / 5898240.0f;
  const float W3 = 0.1f / 6291456.0f;
  const float W4 = 0.1f / 18874368.0f;
  float val = see_p * W1 + see_m * W2 + srg_p * W3 + srg_m * W4;

  #pragma unroll
  for (int o = 32; o > 0; o >>= 1) val += __shfl_down(val, o, 64);
  const int wid = tid >> 6, lane = tid & 63;
  if (lane == 0) s_wsum[wid] = val;
  __syncthreads();
  if (tid == 0) atomicAdd(out, s_wsum[0] + s_wsum[1] + s_wsum[2] + s_wsum[3]);
}

extern "C" void kernel_launch(void* const* d_in, const int* in_sizes, int n_in,
                              void* d_out, int out_size, void* d_ws, size_t ws_size,
                              hipStream_t stream) {
  const float* ik   = (const float*)d_in[1];
  const float* dec  = (const float*)d_in[2];
  const float* tgt  = (const float*)d_in[3];
  const float* mean = (const float*)d_in[4];
  const float* stdv = (const float*)d_in[5];
  const float* offs = (const float*)d_in[6];
  float* out = (float*)d_out;

  hipMemsetAsync(out, 0, sizeof(float), stream);
  fk_loss_kernel<<<dim3(512), dim3(256), 0, stream>>>(ik, dec, tgt, mean, stdv, offs, out);
}

// Round 5
// 34.616 us; speedup vs baseline: 3.5702x; 1.0222x over previous
//
#include <hip/hip_runtime.h>

#define TDIM 4096
#define SBAR() __builtin_amdgcn_sched_barrier(0)

// frame layout: f[0..8]=R (row major), f[9..11]=pos, f[12..15]=parent raw quat
__device__ __forceinline__ void fk_step(float* __restrict__ f,
                                        const float* __restrict__ q,
                                        float o0, float o1, float o2) {
  const float pw = f[12], px = f[13], py = f[14], pz = f[15];
  // loc = conj(parent_q) * q
  float lw = pw*q[0] + px*q[1] + py*q[2] + pz*q[3];
  float lx = pw*q[1] - px*q[0] - py*q[3] + pz*q[2];
  float ly = pw*q[2] + px*q[3] - py*q[0] - pz*q[1];
  float lz = pw*q[3] - px*q[2] + py*q[1] - pz*q[0];
  float n2 = lw*lw + lx*lx + ly*ly + lz*lz;
  float inv = rsqrtf(fmaxf(n2, 1e-16f));
  lw *= inv; lx *= inv; ly *= inv; lz *= inv;
  float xx = lx*lx, yy = ly*ly, zz = lz*lz;
  float xy = lx*ly, xz = lx*lz, yz = ly*lz;
  float wx = lw*lx, wy = lw*ly, wz = lw*lz;
  float m0 = 1.0f-2.0f*(yy+zz), m1 = 2.0f*(xy-wz),      m2 = 2.0f*(xz+wy);
  float m3 = 2.0f*(xy+wz),      m4 = 1.0f-2.0f*(xx+zz), m5 = 2.0f*(yz-wx);
  float m6 = 2.0f*(xz-wy),      m7 = 2.0f*(yz+wx),      m8 = 1.0f-2.0f*(xx+yy);
  f[9]  += f[0]*o0 + f[1]*o1 + f[2]*o2;
  f[10] += f[3]*o0 + f[4]*o1 + f[5]*o2;
  f[11] += f[6]*o0 + f[7]*o1 + f[8]*o2;
  float r0 = f[0]*m0 + f[1]*m3 + f[2]*m6;
  float r1 = f[0]*m1 + f[1]*m4 + f[2]*m7;
  float r2 = f[0]*m2 + f[1]*m5 + f[2]*m8;
  float r3 = f[3]*m0 + f[4]*m3 + f[5]*m6;
  float r4 = f[3]*m1 + f[4]*m4 + f[5]*m7;
  float r5 = f[3]*m2 + f[4]*m5 + f[5]*m8;
  float r6 = f[6]*m0 + f[7]*m3 + f[8]*m6;
  float r7 = f[6]*m1 + f[7]*m4 + f[8]*m7;
  float r8 = f[6]*m2 + f[7]*m5 + f[8]*m8;
  f[0]=r0; f[1]=r1; f[2]=r2; f[3]=r3; f[4]=r4; f[5]=r5; f[6]=r6; f[7]=r7; f[8]=r8;
  f[12]=q[0]; f[13]=q[1]; f[14]=q[2]; f[15]=q[3];
}

__global__ __launch_bounds__(256) void fk_loss_kernel(
    const float* __restrict__ ik,   // (32, 168, 4096)
    const float* __restrict__ dec,  // (32, 176, 4096)
    const float* __restrict__ tgt,  // (32, 176, 4096)
    const float* __restrict__ mean, // (176,)
    const float* __restrict__ stdv, // (176,)
    const float* __restrict__ offs, // (22, 3)
    float* __restrict__ out)
{
  __shared__ float s_mean[176];
  __shared__ float s_std[176];
  __shared__ float s_wsum[4];
  const int tid = threadIdx.x;
  for (int i = tid; i < 176; i += 256) { s_mean[i] = mean[i]; s_std[i] = stdv[i]; }
  __syncthreads();

  const int idx = blockIdx.x * 256 + tid;   // 0 .. 131071
  const int b = idx >> 12;
  const int t = idx & 4095;
  const float* __restrict__ pik  = ik  + ((size_t)b * 168) * TDIM + t;
  const float* __restrict__ pdec = dec + ((size_t)b * 176) * TDIM + t;
  const float* __restrict__ ptgt = tgt + ((size_t)b * 176) * TDIM + t;

  float see_p = 0.f, see_m = 0.f, srg_p = 0.f, srg_m = 0.f;

  float fik[16], fdec[16], ftgt[16];
  float sik[16], sdec[16], stgt[16];
  float rq[4];
  float A[12], B[12], C[12];   // stage buffers: [0..3] ik, [4..7] dec, [8..11] tgt (raw)

#define LOADST(buf, j)                                                         \
  { _Pragma("unroll")                                                          \
    for (int c = 0; c < 4; c++) buf[c]      = pik [(((j)-1)*8 + c) * TDIM];    \
    _Pragma("unroll")                                                          \
    for (int c = 0; c < 4; c++) buf[4 + c]  = pdec[(((j)*8)   + c) * TDIM];    \
    _Pragma("unroll")                                                          \
    for (int c = 0; c < 4; c++) buf[8 + c]  = ptgt[(((j)*8)   + c) * TDIM]; }

#define COMP(buf, j, IS_EE)                                                    \
  { float qi[4], qd[4], qt[4];                                                 \
    _Pragma("unroll")                                                          \
    for (int c = 0; c < 4; c++) {                                              \
      const float sd = s_std[(j)*8 + c], mn = s_mean[(j)*8 + c];               \
      qi[c] = fmaf(buf[c],     sd, mn);                                        \
      qd[c] = fmaf(buf[4+c],   sd, mn);                                        \
      qt[c] = fmaf(buf[8+c],   sd, mn);                                        \
    }                                                                          \
    const float o0 = offs[(j)*3], o1 = offs[(j)*3+1], o2 = offs[(j)*3+2];      \
    fk_step(fik,  qi, o0, o1, o2);                                             \
    fk_step(fdec, qd, o0, o1, o2);                                             \
    fk_step(ftgt, qt, o0, o1, o2);                                             \
    if (IS_EE) {                                                               \
      _Pragma("unroll")                                                        \
      for (int c = 0; c < 3; c++) { float d = fik[9+c] - ftgt[9+c]; see_p = fmaf(d, d, see_p); } \
      _Pragma("unroll")                                                        \
      for (int c = 0; c < 9; c++) { float d = fik[c]   - ftgt[c];   see_m = fmaf(d, d, see_m); } \
    } else {                                                                   \
      _Pragma("unroll")                                                        \
      for (int c = 0; c < 3; c++) { float d = fdec[9+c] - fik[9+c]; srg_p = fmaf(d, d, srg_p); } \
      _Pragma("unroll")                                                        \
      for (int c = 0; c < 9; c++) { float d = fdec[c]   - fik[c];   srg_m = fmaf(d, d, srg_m); } \
    } }

#define RESET()                                                                \
  { _Pragma("unroll")                                                          \
    for (int c = 0; c < 16; c++) { fik[c] = 0.f; fdec[c] = 0.f; ftgt[c] = 0.f; } \
    fik[0]=fik[4]=fik[8]=1.f; fdec[0]=fdec[4]=fdec[8]=1.f; ftgt[0]=ftgt[4]=ftgt[8]=1.f; \
    fik[12]=1.f; fdec[12]=1.f;                                                 \
    ftgt[12]=rq[0]; ftgt[13]=rq[1]; ftgt[14]=rq[2]; ftgt[15]=rq[3]; }

#define SAVE()                                                                 \
  { _Pragma("unroll")                                                          \
    for (int c = 0; c < 16; c++) { sik[c]=fik[c]; sdec[c]=fdec[c]; stgt[c]=ftgt[c]; } }

#define RESTORE()                                                              \
  { _Pragma("unroll")                                                          \
    for (int c = 0; c < 16; c++) { fik[c]=sik[c]; fdec[c]=sdec[c]; ftgt[c]=stgt[c]; } }

  // ---- prime pipeline: 2 stages in flight ----
  float rqr[4];
  #pragma unroll
  for (int c = 0; c < 4; c++) rqr[c] = ptgt[c * TDIM];
  LOADST(A, 1);
  LOADST(B, 2);
  SBAR();
  #pragma unroll
  for (int c = 0; c < 4; c++) rq[c] = fmaf(rqr[c], s_std[c], s_mean[c]);
  RESET();
  // steady state: load j+2, compute j   (buffer of joint j: j%3==1→A, 2→B, 0→C)
  LOADST(C, 3);  COMP(A, 1,  false); SBAR();
  LOADST(A, 4);  COMP(B, 2,  false); SBAR();
  LOADST(B, 5);  COMP(C, 3,  false); SBAR();
  LOADST(C, 6);  COMP(A, 4,  true);  RESET(); SBAR();
  LOADST(A, 7);  COMP(B, 5,  false); SBAR();
  LOADST(B, 8);  COMP(C, 6,  false); SBAR();
  LOADST(C, 9);  COMP(A, 7,  false); SBAR();
  LOADST(A, 10); COMP(B, 8,  true);  RESET(); SBAR();
  LOADST(B, 11); COMP(C, 9,  false); SBAR();
  LOADST(C, 12); COMP(A, 10, false); SBAR();
  LOADST(A, 13); COMP(B, 11, false); SAVE(); SBAR();
  LOADST(B, 14); COMP(C, 12, false); SBAR();
  LOADST(C, 15); COMP(A, 13, true);  RESTORE(); SBAR();
  LOADST(A, 16); COMP(B, 14, false); SBAR();
  LOADST(B, 17); COMP(C, 15, false); SBAR();
  LOADST(C, 18); COMP(A, 16, false); SBAR();
  LOADST(A, 19); COMP(B, 17, true);  RESTORE(); SBAR();
  LOADST(B, 20); COMP(C, 18, false); SBAR();
  LOADST(C, 21); COMP(A, 19, false); SBAR();
  COMP(B, 20, false); SBAR();
  COMP(C, 21, true);

#undef LOADST
#undef COMP
#undef RESET
#undef SAVE
#undef RESTORE

  // weights: see_p/(BT*15) + see_m/(BT*45) + 0.1*(srg_p/(BT*48) + srg_m/(BT*144))
  const float W1 = 1.0f / 1966080.0f;
  const float W2 = 1.0f / 5898240.0f;
  const float W3 = 0.1f / 6291456.0f;
  const float W4 = 0.1f / 18874368.0f;
  float val = see_p * W1 + see_m * W2 + srg_p * W3 + srg_m * W4;

  #pragma unroll
  for (int o = 32; o > 0; o >>= 1) val += __shfl_down(val, o, 64);
  const int wid = tid >> 6, lane = tid & 63;
  if (lane == 0) s_wsum[wid] = val;
  __syncthreads();
  if (tid == 0) atomicAdd(out, s_wsum[0] + s_wsum[1] + s_wsum[2] + s_wsum[3]);
}

extern "C" void kernel_launch(void* const* d_in, const int* in_sizes, int n_in,
                              void* d_out, int out_size, void* d_ws, size_t ws_size,
                              hipStream_t stream) {
  const float* ik   = (const float*)d_in[1];
  const float* dec  = (const float*)d_in[2];
  const float* tgt  = (const float*)d_in[3];
  const float* mean = (const float*)d_in[4];
  const float* stdv = (const float*)d_in[5];
  const float* offs = (const float*)d_in[6];
  float* out = (float*)d_out;

  hipMemsetAsync(out, 0, sizeof(float), stream);
  fk_loss_kernel<<<dim3(512), dim3(256), 0, stream>>>(ik, dec, tgt, mean, stdv, offs, out);
}